// Round 7
// baseline (176.809 us; speedup 1.0000x reference)
//
#include <hip/hip_runtime.h>
#include <stdint.h>

#define N_Q   65536
#define N_S   65536
#define NB_H  26
#define PAD_H 28
#define KP    10
#define CIN   64
#define COUT  128
#define MT    8    // query points per gather block
#define BM    64   // gemm row tile

typedef unsigned short u16x4  __attribute__((ext_vector_type(4)));
typedef unsigned short u16x8  __attribute__((ext_vector_type(8)));
typedef float          f32x4  __attribute__((ext_vector_type(4)));
typedef float          f32x2  __attribute__((ext_vector_type(2)));
typedef _Float16       f16x8  __attribute__((ext_vector_type(8)));
typedef _Float16       f16x2  __attribute__((ext_vector_type(2)));

#define CVT_BLOCKS 2049   // ceil((N_S+1)*CIN/8 / 256)
#define PACK_BLOCKS 40    // ceil(8*20*64 / 256)

static __device__ __forceinline__ unsigned short f2h(float f) {
  return __builtin_bit_cast(unsigned short, (_Float16)f);
}

// v_cvt_pkrtz_f16_f32 packed to raw u32 (builtin returns __fp16x2, not _Float16x2)
static __device__ __forceinline__ unsigned int pkrtz_u32(float a, float b) {
  return __builtin_bit_cast(unsigned int, __builtin_amdgcn_cvt_pkrtz(a, b));
}
static __device__ __forceinline__ float h2f_lo(unsigned int u) {
  return (float)__builtin_bit_cast(_Float16, (unsigned short)(u & 0xffffu));
}
static __device__ __forceinline__ float h2f_hi(unsigned int u) {
  return (float)__builtin_bit_cast(_Float16, (unsigned short)(u >> 16));
}

// ---- prep: x fp32 -> fp16 (+ zero shadow row) AND weight pack (fp16) --------
// Bpack[((ct*20 + ks)*64 + lane)*8 + j] = B[ks*32 + (lane>>4)*8 + j][ct*16 + (lane&15)]
__global__ void prep_kernel(const float* __restrict__ x,
                            const float* __restrict__ w,
                            unsigned short* __restrict__ xh,
                            unsigned short* __restrict__ bp) {
  if (blockIdx.x < CVT_BLOCKS) {
    long t = (long)blockIdx.x * blockDim.x + threadIdx.x;
    long off = t * 8;
    if (off >= (long)(N_S + 1) * CIN) return;
    u16x8 o;
    if (off < (long)N_S * CIN) {
      f32x4 a = *(const f32x4*)(x + off);
      f32x4 b = *(const f32x4*)(x + off + 4);
      o[0] = f2h(a[0]); o[1] = f2h(a[1]); o[2] = f2h(a[2]); o[3] = f2h(a[3]);
      o[4] = f2h(b[0]); o[5] = f2h(b[1]); o[6] = f2h(b[2]); o[7] = f2h(b[3]);
    } else {
      o = (u16x8)0;                       // shadow feature row = zeros
    }
    *(u16x8*)(xh + off) = o;
  } else {
    int t = (blockIdx.x - CVT_BLOCKS) * blockDim.x + threadIdx.x;
    if (t >= 8 * 20 * 64) return;
    int lane = t & 63;
    int frag = t >> 6;            // ct*20 + ks
    int ks = frag % 20;
    int ct = frag / 20;
    int row0 = ks * 32 + (lane >> 4) * 8;
    int col  = ct * 16 + (lane & 15);
    u16x8 o;
    #pragma unroll
    for (int j = 0; j < 8; ++j) o[j] = f2h(w[(row0 + j) * COUT + col]);
    *(u16x8*)(bp + (long)t * 8) = o;
  }
}

// ---- kernel A: phases A,A2,B(sparse-compact),C -> weighted[N][640] fp16 -----
// KEY FACT: w = max(1-d/1.2, 0) is ~95% exactly zero (nbr~N(0,2), kp~N(0,1.93)
// per coord -> P(d<1.2) = P(chi2_3 < 0.366) ~ 5%). Phase B compacts the ~42%
// of neighbor rows that touch ANY kernel point; phase C only gathers/MACs those.
// acc[k] stays statically indexed (dense-k inner) -> no reg indirection/spill.
// LDS ~15.2 KB, VGPR ~50 -> 8 blocks/CU.
__global__ void __launch_bounds__(256, 8)
kpconv_gather(const float* __restrict__ q_pts, const float* __restrict__ s_pts,
              const float* __restrict__ gen_W, const float* __restrict__ gen_b,
              const int* __restrict__ inds, const unsigned short* __restrict__ xh,
              unsigned short* __restrict__ wg) {

  __shared__ int          sh_ind[MT][NB_H];        //  832 B
  __shared__ float        sh_nbr[MT][80];          // 2560 B (78 used + 2 pad=-1)
  __shared__ float        sh_kp[MT][KP * 3];       //  960 B
  __shared__ int          sh_cnt[MT];              //   32 B  active-row count
  __shared__ unsigned int sh_hoff[MT][NB_H];       //  832 B  xh element offset (ind*64)
  __shared__ float        sh_w[MT][NB_H][12];      // 9984 B  fp32 w[10] per active row (pad 12)

  const int tid  = threadIdx.x;
  const int base = blockIdx.x * MT;

  // ---- Phase A: neighbors = s_pad[ind] - q; init counters ----
  if (tid < MT) sh_cnt[tid] = 0;
  if (tid < MT * NB_H) {
    int m = tid / NB_H, h = tid % NB_H;
    int n = base + m;
    int ind = inds[n * NB_H + h];
    sh_ind[m][h] = ind;
    float sx, sy, sz;
    if ((unsigned)ind < (unsigned)N_S) {
      sx = s_pts[ind * 3 + 0]; sy = s_pts[ind * 3 + 1]; sz = s_pts[ind * 3 + 2];
    } else {
      sx = 1e6f; sy = 1e6f; sz = 1e6f;   // shadow support point
    }
    sh_nbr[m][h * 3 + 0] = sx - q_pts[n * 3 + 0];
    sh_nbr[m][h * 3 + 1] = sy - q_pts[n * 3 + 1];
    sh_nbr[m][h * 3 + 2] = sz - q_pts[n * 3 + 2];
  }
  if (tid < MT * 2) sh_nbr[tid >> 1][78 + (tid & 1)] = -1.0f;
  __syncthreads();

  // ---- Phase A2: kp = padded @ gen_W^T + gen_b (float4-vectorized dot) ----
  // channels 0..77 = neighbors, 78..79 = -1 (in sh_nbr), 80..83 folded to bias.
  if (tid < MT * KP * 3) {
    int m = tid / 30, r = tid % 30;
    const float* Wr = gen_W + r * (PAD_H * 3);
    const f32x4* W4 = (const f32x4*)Wr;
    const f32x4* N4 = (const f32x4*)&sh_nbr[m][0];
    f32x4 accv = {0.f, 0.f, 0.f, 0.f};
    #pragma unroll
    for (int j = 0; j < 20; ++j) accv += W4[j] * N4[j];
    sh_kp[m][r] = gen_b[r] - (Wr[80] + Wr[81] + Wr[82] + Wr[83])
                + accv[0] + accv[1] + accv[2] + accv[3];
  }
  __syncthreads();

  // ---- Phase B: per (m,h) compute 10 w's; append row to compact list if any>0
  if (tid < MT * NB_H) {
    int m = tid / NB_H, h = tid % NB_H;
    float nx = sh_nbr[m][h * 3 + 0];
    float ny = sh_nbr[m][h * 3 + 1];
    float nz = sh_nbr[m][h * 3 + 2];
    float wv[KP];
    bool any = false;
    #pragma unroll
    for (int k = 0; k < KP; ++k) {
      float dx = nx - sh_kp[m][k * 3 + 0];
      float dy = ny - sh_kp[m][k * 3 + 1];
      float dz = nz - sh_kp[m][k * 3 + 2];
      float d  = sqrtf(dx * dx + dy * dy + dz * dz);
      float w  = fmaxf(1.0f - d * (1.0f / 1.2f), 0.0f);
      wv[k] = w;
      any = any || (w > 0.0f);
    }
    if (any) {
      int s = atomicAdd(&sh_cnt[m], 1);
      sh_hoff[m][s] = (unsigned int)sh_ind[m][h] * CIN;   // element offset into xh
      #pragma unroll
      for (int k = 0; k < KP; ++k) sh_w[m][s][k] = wv[k];
    }
  }
  __syncthreads();

  // ---- Phase C: weighted[m][k][i0..i0+1] over ACTIVE rows only ----
  // 32 threads/point, 2 channels each; depth-4 statically-slotted prefetch.
  {
    const int m  = tid >> 5;
    const int i0 = (tid & 31) * 2;
    const int c  = sh_cnt[m];
    f32x2 acc[KP];
    #pragma unroll
    for (int k = 0; k < KP; ++k) acc[k] = (f32x2){0.f, 0.f};

    unsigned int xr0 = 0, xr1 = 0, xr2 = 0, xr3 = 0;
    if (0 < c) xr0 = *(const unsigned int*)(xh + sh_hoff[m][0] + i0);
    if (1 < c) xr1 = *(const unsigned int*)(xh + sh_hoff[m][1] + i0);
    if (2 < c) xr2 = *(const unsigned int*)(xh + sh_hoff[m][2] + i0);
    if (3 < c) xr3 = *(const unsigned int*)(xh + sh_hoff[m][3] + i0);

    #define C_BODY(J, XR)                                                     \
      {                                                                       \
        unsigned int cur = XR;                                                \
        if ((J) + 4 < c) XR = *(const unsigned int*)(xh + sh_hoff[m][(J) + 4] + i0); \
        f32x2 xp = { h2f_lo(cur), h2f_hi(cur) };                              \
        f32x4 wa = *(const f32x4*)&sh_w[m][J][0];                             \
        f32x4 wb = *(const f32x4*)&sh_w[m][J][4];                             \
        f32x2 wc = *(const f32x2*)&sh_w[m][J][8];                             \
        acc[0] += (f32x2){wa[0], wa[0]} * xp;                                 \
        acc[1] += (f32x2){wa[1], wa[1]} * xp;                                 \
        acc[2] += (f32x2){wa[2], wa[2]} * xp;                                 \
        acc[3] += (f32x2){wa[3], wa[3]} * xp;                                 \
        acc[4] += (f32x2){wb[0], wb[0]} * xp;                                 \
        acc[5] += (f32x2){wb[1], wb[1]} * xp;                                 \
        acc[6] += (f32x2){wb[2], wb[2]} * xp;                                 \
        acc[7] += (f32x2){wb[3], wb[3]} * xp;                                 \
        acc[8] += (f32x2){wc[0], wc[0]} * xp;                                 \
        acc[9] += (f32x2){wc[1], wc[1]} * xp;                                 \
      }

    for (int j0 = 0; j0 < c; j0 += 4) {
      C_BODY(j0, xr0);
      if (j0 + 1 < c) C_BODY(j0 + 1, xr1);
      if (j0 + 2 < c) C_BODY(j0 + 2, xr2);
      if (j0 + 3 < c) C_BODY(j0 + 3, xr3);
    }
    #undef C_BODY

    #pragma unroll
    for (int k = 0; k < KP; ++k) {
      __builtin_nontemporal_store(
          pkrtz_u32(acc[k][0], acc[k][1]),
          (unsigned int*)(wg + (long)(base + m) * (KP * CIN) + k * CIN + i0));
    }
  }
}

// ---- kernel B: out[65536][128] = wg[65536][640] @ B[640][128] (fp16 MFMA) ---
// BM=64 rows/block, 4 waves x 2 col-tiles, BK=64 double-buffered LDS A-chunks.
__global__ void __launch_bounds__(256, 4)
kpconv_gemm(const unsigned short* __restrict__ wg,
            const unsigned short* __restrict__ bp,
            float* __restrict__ out) {

  __shared__ unsigned short sA[2][BM][72];   // 2 x 9216 B

  const int tid  = threadIdx.x;
  const int wave = tid >> 6;
  const int lane = tid & 63;
  const long row0 = (long)blockIdx.x * BM;

  const int srow = tid >> 3;        // 0..31
  const int scb  = tid & 7;         // col block 0..7

  // stage chunk 0 (NT loads: wg is stream-once, keep bp L2-resident)
  {
    u16x8 a = __builtin_nontemporal_load((const u16x8*)(wg + (row0 + srow) * 640 + scb * 8));
    u16x8 b = __builtin_nontemporal_load((const u16x8*)(wg + (row0 + srow + 32) * 640 + scb * 8));
    *(u16x8*)&sA[0][srow][scb * 8] = a;
    *(u16x8*)&sA[0][srow + 32][scb * 8] = b;
  }

  f32x4 acc[4][2];
  #pragma unroll
  for (int rt = 0; rt < 4; ++rt)
    #pragma unroll
    for (int c = 0; c < 2; ++c) acc[rt][c] = (f32x4){0.f, 0.f, 0.f, 0.f};

  const int ct0  = wave * 2, ct1 = ct0 + 1;
  const int arow = lane & 15;
  const int aq   = lane >> 4;
  int cur = 0;

  for (int kc = 0; kc < 10; ++kc) {
    __syncthreads();
    u16x8 p0, p1;
    if (kc < 9) {   // prefetch next A-chunk, hidden behind MFMA phase
      p0 = __builtin_nontemporal_load((const u16x8*)(wg + (row0 + srow) * 640 + (kc + 1) * 64 + scb * 8));
      p1 = __builtin_nontemporal_load((const u16x8*)(wg + (row0 + srow + 32) * 640 + (kc + 1) * 64 + scb * 8));
    }
    #pragma unroll
    for (int ks2 = 0; ks2 < 2; ++ks2) {
      int ks = kc * 2 + ks2;
      u16x8 b0u = *(const u16x8*)(bp + (long)((ct0 * 20 + ks) * 64 + lane) * 8);
      u16x8 b1u = *(const u16x8*)(bp + (long)((ct1 * 20 + ks) * 64 + lane) * 8);
      f16x8 b0 = __builtin_bit_cast(f16x8, b0u);
      f16x8 b1 = __builtin_bit_cast(f16x8, b1u);
      #pragma unroll
      for (int rt = 0; rt < 4; ++rt) {
        u16x8 au = *(const u16x8*)&sA[cur][rt * 16 + arow][ks2 * 32 + aq * 8];
        f16x8 a = __builtin_bit_cast(f16x8, au);
        acc[rt][0] = __builtin_amdgcn_mfma_f32_16x16x32_f16(a, b0, acc[rt][0], 0, 0, 0);
        acc[rt][1] = __builtin_amdgcn_mfma_f32_16x16x32_f16(a, b1, acc[rt][1], 0, 0, 0);
      }
    }
    if (kc < 9) {
      *(u16x8*)&sA[1 - cur][srow][scb * 8] = p0;
      *(u16x8*)&sA[1 - cur][srow + 32][scb * 8] = p1;
      cur ^= 1;
    }
  }

  // C/D layout: col = lane&15, row = (lane>>4)*4 + reg  [measured m89/m91]
  const int col   = lane & 15;
  const int rbase = aq * 4;
  #pragma unroll
  for (int rt = 0; rt < 4; ++rt)
    #pragma unroll
    for (int r = 0; r < 4; ++r) {
      long row = row0 + rt * 16 + rbase + r;
      __builtin_nontemporal_store(acc[rt][0][r], &out[row * COUT + ct0 * 16 + col]);
      __builtin_nontemporal_store(acc[rt][1][r], &out[row * COUT + ct1 * 16 + col]);
    }
}

extern "C" void kernel_launch(void* const* d_in, const int* in_sizes, int n_in,
                              void* d_out, int out_size, void* d_ws, size_t ws_size,
                              hipStream_t stream) {
  const float* q_pts = (const float*)d_in[0];
  const float* s_pts = (const float*)d_in[1];
  const float* x     = (const float*)d_in[2];
  const float* gen_W = (const float*)d_in[3];
  const float* gen_b = (const float*)d_in[4];
  const float* wts   = (const float*)d_in[5];
  const int*   inds  = (const int*)d_in[6];
  float* out = (float*)d_out;

  unsigned short* xh = (unsigned short*)d_ws;            // (N_S+1)*CIN fp16 = 8.39 MB
  unsigned short* bp = xh + (size_t)(N_S + 1) * CIN;     // 81920 fp16 = 160 KB
  unsigned short* wg = bp + (size_t)81920;               // N_Q*640 fp16 = 83.9 MB

  prep_kernel<<<CVT_BLOCKS + PACK_BLOCKS, 256, 0, stream>>>(x, wts, xh, bp);
  kpconv_gather<<<N_Q / MT, 256, 0, stream>>>(q_pts, s_pts, gen_W, gen_b,
                                              inds, xh, wg);
  kpconv_gemm<<<N_Q / BM, 256, 0, stream>>>(wg, bp, out);
}